// Round 8
// baseline (235.502 us; speedup 1.0000x reference)
//
#include <hip/hip_runtime.h>
#include <hip/hip_bf16.h>

#define BB 8
#define CH 256
#define C8 32
#define NP 4096   // 64*64

typedef __attribute__((ext_vector_type(8))) short bf16x8;
typedef __attribute__((ext_vector_type(4))) float f32x4;

#define MFMA16(a, b, c) __builtin_amdgcn_mfma_f32_16x16x32_bf16(a, b, c, 0, 0, 0)
#define SBAR() __builtin_amdgcn_sched_barrier(0)

#if __has_builtin(__builtin_amdgcn_exp2f)
#define EXP2(x) __builtin_amdgcn_exp2f(x)
#else
#define EXP2(x) exp2f(x)
#endif

#define LOG2E 1.44269504088896340736f

__device__ __forceinline__ void async_copy16(const void* src, void* dst_lds) {
    __builtin_amdgcn_global_load_lds(
        (const __attribute__((address_space(1))) unsigned int*)src,
        (__attribute__((address_space(3))) unsigned int*)dst_lds, 16, 0, 0);
}

__device__ __forceinline__ unsigned pk2(float a, float b) {
    union { __hip_bfloat16 h[2]; unsigned u; } x;
    x.h[0] = __float2bfloat16(a);
    x.h[1] = __float2bfloat16(b);
    return x.u;
}

// Stage a [nrows][64] bf16 LDS panel (128B rows, XOR-swizzled: data k-chunk t
// of row r lives at slot t^(r&7)) from row-major bf16 global.
__device__ __forceinline__ void stage_panel64(
    const __hip_bfloat16* __restrict__ src, int rowStride, int k0,
    __hip_bfloat16* lds, int nrows, int w, int l)
{
    const int nslots = nrows * 8;
    for (int S0 = w*64; S0 < nslots; S0 += 256) {
        int S = S0 + l;
        int r = S >> 3, s = S & 7;
        int jb = s ^ (r & 7);
        async_copy16(src + (size_t)r*rowStride + k0 + jb*8,
                     (char*)lds + (size_t)S0*16);
    }
}

__device__ __forceinline__ bf16x8 frag64(const __hip_bfloat16* lds, int r, int t) {
    return *(const bf16x8*)((const char*)lds + r*128 + ((t ^ (r & 7)) << 4));
}

// In-wave P-fragment exchange: lane (g,li) holds packed words W[jb][wi]
// (j = jb*16 + g*4 + {2wi,2wi+1}); returns A-frag bf16x8 with
// j = ks*32 + g*8 .. +8 for this lane's i = li. Verified vs v6 ps semantics.
__device__ __forceinline__ bf16x8 exchange_p(const unsigned Wt[4][2], int g, int ks) {
    unsigned v16_0, v16_1, vc_0, vc_1;
    if (g & 2) {
        v16_0 = Wt[ks*2+1][0]; v16_1 = Wt[ks*2+1][1];
        vc_0  = Wt[ks*2+0][0]; vc_1  = Wt[ks*2+0][1];
    } else {
        v16_0 = Wt[ks*2+0][0]; v16_1 = Wt[ks*2+0][1];
        vc_0  = Wt[ks*2+1][0]; vc_1  = Wt[ks*2+1][1];
    }
    unsigned x16_0 = (unsigned)__shfl_xor((int)v16_0, 16);
    unsigned x16_1 = (unsigned)__shfl_xor((int)v16_1, 16);
    unsigned x32_0 = (unsigned)__shfl_xor((int)vc_0, 32);
    unsigned x32_1 = (unsigned)__shfl_xor((int)vc_1, 32);
    unsigned x48_0 = (unsigned)__shfl_xor((int)vc_0, 48);
    unsigned x48_1 = (unsigned)__shfl_xor((int)vc_1, 48);
    unsigned r0 = (g==0) ? v16_0 : (g==1) ? x48_0 : (g==2) ? x32_0 : x16_0;
    unsigned r1 = (g==0) ? v16_1 : (g==1) ? x48_1 : (g==2) ? x32_1 : x16_1;
    unsigned r2 = (g==0) ? x16_0 : (g==1) ? x32_0 : (g==2) ? x48_0 : v16_0;
    unsigned r3 = (g==0) ? x16_1 : (g==1) ? x32_1 : (g==2) ? x48_1 : v16_1;
    union { unsigned u[4]; bf16x8 v; } res;
    res.u[0] = r0; res.u[1] = r1; res.u[2] = r2; res.u[3] = r3;
    return res.v;
}

// -------------------- K0a: weights -> bf16 ----------------------------------
__global__ __launch_bounds__(256) void convert_w(
    const float* __restrict__ wq, const float* __restrict__ wk,
    const float* __restrict__ wv,
    __hip_bfloat16* __restrict__ wqkb, __hip_bfloat16* __restrict__ wvb)
{
    int id = blockIdx.x * 256 + threadIdx.x;
    if (id < 64*256) {
        float v = (id < 32*256) ? wq[id] : wk[id - 32*256];
        wqkb[id] = __float2bfloat16(v);
    } else {
        int j = id - 64*256;
        wvb[j] = __float2bfloat16(wv[j]);
    }
}

// ------------- K0b: x -> xbT [B][N][C] bf16 + xb [B][C][N] bf16 -------------
__global__ __launch_bounds__(256) void convert_T(
    const float* __restrict__ x, __hip_bfloat16* __restrict__ xbT,
    __hip_bfloat16* __restrict__ xb)
{
    int b = blockIdx.z, c0 = blockIdx.y * 64, n0 = blockIdx.x * 64;
    __shared__ float t[64][65];
    int tid = threadIdx.x;
    int nn = tid & 63, ch = tid >> 6;
    const float* xp = x + (size_t)b*CH*NP + (size_t)c0*NP + n0;
    #pragma unroll
    for (int u = 0; u < 16; ++u) {
        float v = xp[(size_t)(ch + u*4)*NP + nn];
        t[ch + u*4][nn] = v;
        xb[((size_t)b*CH + c0 + ch + u*4)*NP + n0 + nn] = __float2bfloat16(v);
    }
    __syncthreads();
    int n = tid >> 2, seg = tid & 3;
    union { __hip_bfloat16 h[16]; bf16x8 v[2]; } u16;
    #pragma unroll
    for (int u = 0; u < 16; ++u)
        u16.h[u] = __float2bfloat16(t[seg*16 + u][n]);
    __hip_bfloat16* dst = xbT + ((size_t)b*NP + n0 + n)*CH + c0 + seg*16;
    *(bf16x8*)dst = u16.v[0];
    *(bf16x8*)(dst + 8) = u16.v[1];
}

// -------------------- K1: q,k projections (MFMA) ----------------------------
// D[n][o] = sum_d xbT[n][d] * wqk[o][d];  o<32 -> q (scaled by log2e), else k.
__global__ __launch_bounds__(256) void qk_kernel(
    const __hip_bfloat16* __restrict__ xbT, const __hip_bfloat16* __restrict__ wqkb,
    const float* __restrict__ bq, const float* __restrict__ bk,
    __hip_bfloat16* __restrict__ qt, __hip_bfloat16* __restrict__ kt)
{
    const int b = blockIdx.y, n0 = blockIdx.x * 128;
    const int tid = threadIdx.x;
    const int w = tid >> 6, l = tid & 63, g = l >> 4, li = l & 15;

    __shared__ __align__(16) __hip_bfloat16 Ap[128*64];
    __shared__ __align__(16) __hip_bfloat16 Bp[64*64];

    f32x4 acc[2][4];
    #pragma unroll
    for (int mf = 0; mf < 2; ++mf)
        #pragma unroll
        for (int nf = 0; nf < 4; ++nf) acc[mf][nf] = (f32x4){0.f,0.f,0.f,0.f};

    const __hip_bfloat16* asrc = xbT + ((size_t)b*NP + n0)*CH;
    for (int kt4 = 0; kt4 < 4; ++kt4) {
        stage_panel64(asrc, CH, kt4*64, Ap, 128, w, l);
        stage_panel64(wqkb, CH, kt4*64, Bp, 64, w, l);
        __syncthreads();
        #pragma unroll
        for (int ks = 0; ks < 2; ++ks) {
            bf16x8 af[2], bf[4];
            #pragma unroll
            for (int mf = 0; mf < 2; ++mf) af[mf] = frag64(Ap, w*32 + mf*16 + li, ks*4 + g);
            #pragma unroll
            for (int nf = 0; nf < 4; ++nf) bf[nf] = frag64(Bp, nf*16 + li, ks*4 + g);
            #pragma unroll
            for (int mf = 0; mf < 2; ++mf)
                #pragma unroll
                for (int nf = 0; nf < 4; ++nf)
                    acc[mf][nf] = MFMA16(af[mf], bf[nf], acc[mf][nf]);
        }
        __syncthreads();
    }
    #pragma unroll
    for (int mf = 0; mf < 2; ++mf)
        #pragma unroll
        for (int nf = 0; nf < 4; ++nf)
            #pragma unroll
            for (int q = 0; q < 4; ++q) {
                int n = n0 + w*32 + mf*16 + g*4 + q;
                int o = nf*16 + li;
                float bias = (o < 32) ? bq[o] : bk[o - 32];
                float scl  = (o < 32) ? LOG2E : 1.0f;
                __hip_bfloat16* dst = (o < 32) ? qt : kt;
                dst[((size_t)b*NP + n)*C8 + (o & 31)] =
                    __float2bfloat16((acc[mf][nf][q] + bias) * scl);
            }
}

// -------------------- K2: v projection (MFMA) -> vb [B][C][N] ---------------
__global__ __launch_bounds__(256) void v_kernel(
    const __hip_bfloat16* __restrict__ xbT, const __hip_bfloat16* __restrict__ wvb,
    const float* __restrict__ bv, __hip_bfloat16* __restrict__ vb)
{
    const int b = blockIdx.y, n0 = blockIdx.x * 64;
    const int tid = threadIdx.x;
    const int w = tid >> 6, l = tid & 63, g = l >> 4, li = l & 15;

    __shared__ __align__(16) char smem[40960];
    __hip_bfloat16* Ap = (__hip_bfloat16*)smem;
    __hip_bfloat16* Bp = (__hip_bfloat16*)(smem + 32768);
    __hip_bfloat16* vt = (__hip_bfloat16*)smem;

    f32x4 acc[4][4];
    #pragma unroll
    for (int mf = 0; mf < 4; ++mf)
        #pragma unroll
        for (int nf = 0; nf < 4; ++nf) acc[mf][nf] = (f32x4){0.f,0.f,0.f,0.f};

    const __hip_bfloat16* bsrc = xbT + ((size_t)b*NP + n0)*CH;
    for (int kt4 = 0; kt4 < 4; ++kt4) {
        stage_panel64(wvb, CH, kt4*64, Ap, 256, w, l);
        stage_panel64(bsrc, CH, kt4*64, Bp, 64, w, l);
        __syncthreads();
        #pragma unroll
        for (int ks = 0; ks < 2; ++ks) {
            bf16x8 af[4], bf[4];
            #pragma unroll
            for (int mf = 0; mf < 4; ++mf) af[mf] = frag64(Ap, w*64 + mf*16 + li, ks*4 + g);
            #pragma unroll
            for (int nf = 0; nf < 4; ++nf) bf[nf] = frag64(Bp, nf*16 + li, ks*4 + g);
            #pragma unroll
            for (int mf = 0; mf < 4; ++mf)
                #pragma unroll
                for (int nf = 0; nf < 4; ++nf)
                    acc[mf][nf] = MFMA16(af[mf], bf[nf], acc[mf][nf]);
        }
        __syncthreads();
    }
    #pragma unroll
    for (int mf = 0; mf < 4; ++mf)
        #pragma unroll
        for (int nf = 0; nf < 4; ++nf)
            #pragma unroll
            for (int q = 0; q < 4; ++q) {
                int c = w*64 + mf*16 + g*4 + q;
                int n = nf*16 + li;
                vt[c*72 + n] = __float2bfloat16(acc[mf][nf][q] + bv[c]);
            }
    __syncthreads();
    for (int S = tid; S < 2048; S += 256) {
        int c = S >> 3, s = S & 7;
        bf16x8 v = *(const bf16x8*)((const char*)vt + c*144 + s*16);
        *(bf16x8*)(vb + ((size_t)b*CH + c)*NP + n0 + s*8) = v;
    }
}

// -------------------- K3: CAM energy partials (MFMA, bf16 DMA staging) ------
__global__ __launch_bounds__(256) void energy_kernel(
    const __hip_bfloat16* __restrict__ xb, float* __restrict__ E_part)
{
    const int rh = blockIdx.x, kp = blockIdx.y, b = blockIdx.z;
    const int tid = threadIdx.x;
    const int w = tid >> 6, l = tid & 63, g = l >> 4, li = l & 15;

    __shared__ __align__(16) __hip_bfloat16 P[256*64];

    f32x4 acc[16];
    #pragma unroll
    for (int nf = 0; nf < 16; ++nf) acc[nf] = (f32x4){0.f,0.f,0.f,0.f};

    const __hip_bfloat16* xp = xb + (size_t)b*CH*NP;
    for (int kt4 = 0; kt4 < 16; ++kt4) {
        int k0 = kp*1024 + kt4*64;
        stage_panel64(xp, NP, k0, P, 256, w, l);
        __syncthreads();
        #pragma unroll
        for (int ks = 0; ks < 2; ++ks) {
            bf16x8 af = frag64(P, rh*64 + w*16 + li, ks*4 + g);
            #pragma unroll
            for (int nf = 0; nf < 16; ++nf) {
                bf16x8 bf = frag64(P, nf*16 + li, ks*4 + g);
                acc[nf] = MFMA16(af, bf, acc[nf]);
            }
        }
        __syncthreads();
    }
    #pragma unroll
    for (int nf = 0; nf < 16; ++nf)
        #pragma unroll
        for (int q = 0; q < 4; ++q) {
            int r = rh*64 + w*16 + g*4 + q;
            int c = nf*16 + li;
            E_part[(((size_t)b*4 + kp)*CH + r)*CH + c] = acc[nf][q];
        }
}

// -------------------- K4: softmax over C (fused partial reduce) -> bf16 -----
__global__ __launch_bounds__(256) void cam_softmax(
    const float* __restrict__ E_part, __hip_bfloat16* __restrict__ attnb)
{
    int b = blockIdx.y, r = blockIdx.x;
    int tid = threadIdx.x;
    int lane = tid & 63, wid = tid >> 6;
    const float* base = E_part + ((size_t)b*4*CH + r)*CH + tid;
    float e = base[0] + base[CH*CH] + base[2*CH*CH] + base[3*CH*CH];

    __shared__ float redm[4], reds[4];
    float m = e;
    #pragma unroll
    for (int off = 32; off >= 1; off >>= 1) m = fmaxf(m, __shfl_xor(m, off));
    if (lane == 0) redm[wid] = m;
    __syncthreads();
    m = fmaxf(fmaxf(redm[0], redm[1]), fmaxf(redm[2], redm[3]));

    float p = __expf(e - m);
    float s = p;
    #pragma unroll
    for (int off = 32; off >= 1; off >>= 1) s += __shfl_xor(s, off);
    if (lane == 0) reds[wid] = s;
    __syncthreads();
    s = reds[0] + reds[1] + reds[2] + reds[3];
    attnb[((size_t)b*CH + r)*CH + tid] = __float2bfloat16(p / s);
}

// -------------------- K5: out = gamma*(A@X) + x (MFMA) ----------------------
__global__ __launch_bounds__(256) void apply_kernel(
    const __hip_bfloat16* __restrict__ attnb, const __hip_bfloat16* __restrict__ xbT,
    const float* __restrict__ x, const float* __restrict__ gamma,
    float* __restrict__ out)
{
    const int b = blockIdx.y, n0 = blockIdx.x * 64;
    const int tid = threadIdx.x;
    const int w = tid >> 6, l = tid & 63, g = l >> 4, li = l & 15;

    __shared__ __align__(16) __hip_bfloat16 Ap[256*64];
    __shared__ __align__(16) __hip_bfloat16 Bp[64*64];

    f32x4 acc[4][4];
    #pragma unroll
    for (int mf = 0; mf < 4; ++mf)
        #pragma unroll
        for (int nf = 0; nf < 4; ++nf) acc[mf][nf] = (f32x4){0.f,0.f,0.f,0.f};

    const __hip_bfloat16* asrc = attnb + (size_t)b*CH*CH;
    const __hip_bfloat16* bsrc = xbT + ((size_t)b*NP + n0)*CH;
    for (int kt4 = 0; kt4 < 4; ++kt4) {
        stage_panel64(asrc, CH, kt4*64, Ap, 256, w, l);
        stage_panel64(bsrc, CH, kt4*64, Bp, 64, w, l);
        __syncthreads();
        #pragma unroll
        for (int ks = 0; ks < 2; ++ks) {
            bf16x8 af[4], bf[4];
            #pragma unroll
            for (int mf = 0; mf < 4; ++mf) af[mf] = frag64(Ap, w*64 + mf*16 + li, ks*4 + g);
            #pragma unroll
            for (int nf = 0; nf < 4; ++nf) bf[nf] = frag64(Bp, nf*16 + li, ks*4 + g);
            #pragma unroll
            for (int mf = 0; mf < 4; ++mf)
                #pragma unroll
                for (int nf = 0; nf < 4; ++nf)
                    acc[mf][nf] = MFMA16(af[mf], bf[nf], acc[mf][nf]);
        }
        __syncthreads();
    }
    float g0 = gamma[0];
    #pragma unroll
    for (int mf = 0; mf < 4; ++mf)
        #pragma unroll
        for (int nf = 0; nf < 4; ++nf)
            #pragma unroll
            for (int q = 0; q < 4; ++q) {
                int c = w*64 + mf*16 + g*4 + q;
                int n = n0 + nf*16 + li;
                size_t idx = ((size_t)b*CH + c)*NP + n;
                out[idx] = g0*acc[mf][nf][q] + x[idx];
            }
}

// ---- K6: PAM flash v8 — in-register P exchange, 1 barrier/iter -------------
// 8 waves: wave = (ih = i-quarter of 128-row tile, cq = c-half).
// QK^T gives lane-local P columns; exchange_p builds PV A-frags in-register.
// Shared V LDS dbuf; own-vmcnt(0) before the single barrier; K/Q from global.
__global__ __launch_bounds__(512) void pam_flash(
    const __hip_bfloat16* __restrict__ qg,   // [B][N][32] (pre-scaled)
    const __hip_bfloat16* __restrict__ kg,   // [B][N][32]
    const __hip_bfloat16* __restrict__ vg,   // [B][C][N]
    float* __restrict__ out)
{
    const int bid = blockIdx.x;
    const int b   = bid & 7;                 // batch -> XCD pin
    const int i0  = (bid >> 3) * 128;
    const int tid = threadIdx.x;
    const int w   = tid >> 6;                // 0..7
    const int ih  = w >> 1;                  // i-quarter (32 rows)
    const int cq  = w & 1;                   // c-half (128 channels)
    const int l   = tid & 63;
    const int g   = l >> 4;
    const int li  = l & 15;

    __shared__ __align__(16) __hip_bfloat16 vsb[2][256*64];  // 64KB V dbuf

    // V staging: 4 copies/wave; slot S16 = it*512 + w*64 + l
    // c = it*64 + w*8 + (l>>3); data chunk jb = (l&7) ^ (l>>3)
    const int cb  = w*8 + (l >> 3);
    const int jbv = (l & 7) ^ (l >> 3);
    const char* vsrc0 = (const char*)vg + ((size_t)(b*CH + cb)*NP + jbv*8)*2;

#define ISSUE_V(JT, BUF)                                                        \
    {                                                                           \
        _Pragma("unroll")                                                       \
        for (int it = 0; it < 4; ++it)                                          \
            async_copy16(vsrc0 + (size_t)it*(64*NP*2) + (size_t)(JT)*128,       \
                         (char*)vsb[BUF] + it*8192 + w*1024);                   \
    }

    // K rows j = jt*64 + jb*16 + li, chunk g  (1KB coalesced per (jb))
    const char* kbase = (const char*)kg + (size_t)b*NP*64 + li*64 + g*16;
#define LOADK(DST, JT)                                                          \
    {                                                                           \
        _Pragma("unroll")                                                       \
        for (int jb = 0; jb < 4; ++jb)                                          \
            DST[jb] = *(const bf16x8*)(kbase + (size_t)((JT)*64 + jb*16)*64);   \
    }

    // Q frags: i = i0 + ih*32 + t*16 + li
    const char* qbase = (const char*)qg + ((size_t)b*NP + i0 + ih*32)*64;

    // ---- prologue: K(0), Q, V(0), K(1) ----
    bf16x8 kA[4], kB[4];
    LOADK(kA, 0);
    bf16x8 qf0 = *(const bf16x8*)(qbase + li*64 + g*16);
    bf16x8 qf1 = *(const bf16x8*)(qbase + (16 + li)*64 + g*16);
    ISSUE_V(0, 0);
    LOADK(kB, 1);
    SBAR();

    f32x4 acc0[8], acc1[8];
    #pragma unroll
    for (int ct = 0; ct < 8; ++ct) {
        acc0[ct] = (f32x4){0.f, 0.f, 0.f, 0.f};
        acc1[ct] = (f32x4){0.f, 0.f, 0.f, 0.f};
    }
    float lacc0 = 0.f, lacc1 = 0.f;

#define PAM_STEP(JT, KREG, BUF)                                                 \
    {                                                                           \
        f32x4 z = (f32x4){0.f, 0.f, 0.f, 0.f};                                  \
        f32x4 st0[4], st1[4];                                                   \
        _Pragma("unroll")                                                       \
        for (int jb = 0; jb < 4; ++jb) {                                        \
            st0[jb] = MFMA16(KREG[jb], qf0, z);                                 \
            st1[jb] = MFMA16(KREG[jb], qf1, z);                                 \
        }                                                                       \
        unsigned W0[4][2], W1[4][2];                                            \
        _Pragma("unroll")                                                       \
        for (int jb = 0; jb < 4; ++jb) {                                        \
            float a0 = EXP2(st0[jb][0]), a1 = EXP2(st0[jb][1]);                 \
            float a2 = EXP2(st0[jb][2]), a3 = EXP2(st0[jb][3]);                 \
            lacc0 += (a0 + a1) + (a2 + a3);                                     \
            W0[jb][0] = pk2(a0, a1); W0[jb][1] = pk2(a2, a3);                   \
            float b0 = EXP2(st1[jb][0]), b1 = EXP2(st1[jb][1]);                 \
            float b2 = EXP2(st1[jb][2]), b3 = EXP2(st1[jb][3]);                 \
            lacc1 += (b0 + b1) + (b2 + b3);                                     \
            W1[jb][0] = pk2(b0, b1); W1[jb][1] = pk2(b2, b3);                   \
        }                                                                       \
        bf16x8 pa00 = exchange_p(W0, g, 0);                                     \
        bf16x8 pa01 = exchange_p(W0, g, 1);                                     \
        bf16x8 pa10 = exchange_p(W1, g, 0);                                     \
        bf16x8 pa11 = exchange_p(W1, g, 1);                                     \
        asm volatile("s_waitcnt vmcnt(0)" ::: "memory");                        \
        SBAR();                                                                 \
        __builtin_amdgcn_s_barrier();                                           \
        SBAR();                                                                 \
        if ((JT) < 62) LOADK(KREG, (JT) + 2);                                   \
        if ((JT) < 63) ISSUE_V((JT) + 1, (BUF) ^ 1);                            \
        SBAR();                                                                 \
        __builtin_amdgcn_s_setprio(1);                                          \
        {                                                                       \
            const char* vb = (const char*)vsb[BUF];                             \
            _Pragma("unroll")                                                   \
            for (int ct = 0; ct < 8; ++ct) {                                    \
                int c = cq*128 + ct*16 + li;                                    \
                bf16x8 bv0 = *(const bf16x8*)(vb + c*128 +                      \
                                ((g ^ (c & 7)) << 4));                          \
                bf16x8 bv1 = *(const bf16x8*)(vb + c*128 +                      \
                                (((4 + g) ^ (c & 7)) << 4));                    \
                acc0[ct] = MFMA16(pa00, bv0, acc0[ct]);                         \
                acc0[ct] = MFMA16(pa01, bv1, acc0[ct]);                         \
                acc1[ct] = MFMA16(pa10, bv0, acc1[ct]);                         \
                acc1[ct] = MFMA16(pa11, bv1, acc1[ct]);                         \
            }                                                                   \
        }                                                                       \
        __builtin_amdgcn_s_setprio(0);                                          \
        SBAR();                                                                 \
    }

    for (int jt = 0; jt < 64; jt += 2) {
        PAM_STEP(jt,     kA, 0);
        PAM_STEP(jt + 1, kB, 1);
    }

    // ---- reduce l over lane groups; redistribute per output row ----
    lacc0 += __shfl_xor(lacc0, 16); lacc0 += __shfl_xor(lacc0, 32);
    lacc1 += __shfl_xor(lacc1, 16); lacc1 += __shfl_xor(lacc1, 32);
    float linv0[4], linv1[4];
    #pragma unroll
    for (int r = 0; r < 4; ++r) {
        int src = (l & 48) | (g*4 + r);     // lane with li' = g*4+r, same g
        linv0[r] = 1.0f / __shfl(lacc0, src);
        linv1[r] = 1.0f / __shfl(lacc1, src);
    }

    #pragma unroll
    for (int ct = 0; ct < 8; ++ct) {
        int c = cq*128 + ct*16 + li;
        size_t base0 = ((size_t)b*CH + c)*NP + i0 + ih*32 + g*4;
        float4 o0 = *(float4*)(out + base0);
        o0.x += acc0[ct][0]*linv0[0];
        o0.y += acc0[ct][1]*linv0[1];
        o0.z += acc0[ct][2]*linv0[2];
        o0.w += acc0[ct][3]*linv0[3];
        *(float4*)(out + base0) = o0;
        size_t base1 = base0 + 16;
        float4 o1 = *(float4*)(out + base1);
        o1.x += acc1[ct][0]*linv1[0];
        o1.y += acc1[ct][1]*linv1[1];
        o1.z += acc1[ct][2]*linv1[2];
        o1.w += acc1[ct][3]*linv1[3];
        *(float4*)(out + base1) = o1;
    }
#undef PAM_STEP
#undef ISSUE_V
#undef LOADK
}

// ---------------------------------------------------------------------------
extern "C" void kernel_launch(void* const* d_in, const int* in_sizes, int n_in,
                              void* d_out, int out_size, void* d_ws, size_t ws_size,
                              hipStream_t stream)
{
    const float* x     = (const float*)d_in[0];
    const float* gamma = (const float*)d_in[1];
    const float* wq    = (const float*)d_in[2];
    const float* bq    = (const float*)d_in[3];
    const float* wk    = (const float*)d_in[4];
    const float* bk    = (const float*)d_in[5];
    const float* wv    = (const float*)d_in[6];
    const float* bv    = (const float*)d_in[7];
    float* out = (float*)d_out;

    char* ws = (char*)d_ws;
    __hip_bfloat16* xbT   = (__hip_bfloat16*)ws;                 ws += (size_t)BB*NP*CH*2;
    __hip_bfloat16* xb    = (__hip_bfloat16*)ws;                 ws += (size_t)BB*CH*NP*2;
    __hip_bfloat16* qtb   = (__hip_bfloat16*)ws;                 ws += (size_t)BB*NP*C8*2;
    __hip_bfloat16* ktb   = (__hip_bfloat16*)ws;                 ws += (size_t)BB*NP*C8*2;
    __hip_bfloat16* vbb   = (__hip_bfloat16*)ws;                 ws += (size_t)BB*CH*NP*2;
    __hip_bfloat16* wqkb  = (__hip_bfloat16*)ws;                 ws += 64*CH*2;
    __hip_bfloat16* wvb   = (__hip_bfloat16*)ws;                 ws += CH*CH*2;
    float*          Epart = (float*)ws;                          ws += (size_t)BB*4*CH*CH*4;
    __hip_bfloat16* attnb = (__hip_bfloat16*)ws;                 ws += (size_t)BB*CH*CH*2;

    convert_w    <<<dim3(320),        256, 0, stream>>>(wq, wk, wv, wqkb, wvb);
    convert_T    <<<dim3(64, 4, BB),  256, 0, stream>>>(x, xbT, xb);
    qk_kernel    <<<dim3(32, BB),     256, 0, stream>>>(xbT, wqkb, bq, bk, qtb, ktb);
    v_kernel     <<<dim3(64, BB),     256, 0, stream>>>(xbT, wvb, bv, vbb);
    energy_kernel<<<dim3(4, 4, BB),   256, 0, stream>>>(xb, Epart);
    cam_softmax  <<<dim3(CH, BB),     256, 0, stream>>>(Epart, attnb);
    apply_kernel <<<dim3(64, BB),     256, 0, stream>>>(attnb, xbT, x, gamma, out);
    pam_flash    <<<dim3(256),        512, 0, stream>>>(qtb, ktb, vbb, out);
}

// Round 9
// 205.257 us; speedup vs baseline: 1.1473x; 1.1473x over previous
//
#include <hip/hip_runtime.h>
#include <hip/hip_bf16.h>

#define BB 8
#define CH 256
#define C8 32
#define NP 4096   // 64*64

typedef __attribute__((ext_vector_type(8))) short bf16x8;
typedef __attribute__((ext_vector_type(4))) float f32x4;
typedef __attribute__((ext_vector_type(16))) float f32x16;

#define MFMA16(a, b, c) __builtin_amdgcn_mfma_f32_16x16x32_bf16(a, b, c, 0, 0, 0)
#define MFMA32(a, b, c) __builtin_amdgcn_mfma_f32_32x32x16_bf16(a, b, c, 0, 0, 0)
#define SBAR() __builtin_amdgcn_sched_barrier(0)

#if __has_builtin(__builtin_amdgcn_exp2f)
#define EXP2(x) __builtin_amdgcn_exp2f(x)
#else
#define EXP2(x) exp2f(x)
#endif

#define LOG2E 1.44269504088896340736f

__device__ __forceinline__ void async_copy16(const void* src, void* dst_lds) {
    __builtin_amdgcn_global_load_lds(
        (const __attribute__((address_space(1))) unsigned int*)src,
        (__attribute__((address_space(3))) unsigned int*)dst_lds, 16, 0, 0);
}

__device__ __forceinline__ unsigned pk2(float a, float b) {
    union { __hip_bfloat16 h[2]; unsigned u; } x;
    x.h[0] = __float2bfloat16(a);
    x.h[1] = __float2bfloat16(b);
    return x.u;
}

// v_permlane32_swap_b32: a[32..63] <-> b[0..31]; both registers updated.
__device__ __forceinline__ void plswap(unsigned &a, unsigned &b) {
    asm volatile("v_permlane32_swap_b32 %0, %1" : "+v"(a), "+v"(b));
}

__device__ __forceinline__ f32x16 zero16() {
    f32x16 z;
    #pragma unroll
    for (int e = 0; e < 16; ++e) z[e] = 0.f;
    return z;
}

// Stage a [nrows][64] bf16 LDS panel (128B rows, XOR-swizzled: data k-chunk t
// of row r lives at slot t^(r&7)) from row-major bf16 global.
__device__ __forceinline__ void stage_panel64(
    const __hip_bfloat16* __restrict__ src, int rowStride, int k0,
    __hip_bfloat16* lds, int nrows, int w, int l)
{
    const int nslots = nrows * 8;
    for (int S0 = w*64; S0 < nslots; S0 += 256) {
        int S = S0 + l;
        int r = S >> 3, s = S & 7;
        int jb = s ^ (r & 7);
        async_copy16(src + (size_t)r*rowStride + k0 + jb*8,
                     (char*)lds + (size_t)S0*16);
    }
}

__device__ __forceinline__ bf16x8 frag64(const __hip_bfloat16* lds, int r, int t) {
    return *(const bf16x8*)((const char*)lds + r*128 + ((t ^ (r & 7)) << 4));
}

// -------------------- K0a: weights -> bf16 ----------------------------------
__global__ __launch_bounds__(256) void convert_w(
    const float* __restrict__ wq, const float* __restrict__ wk,
    const float* __restrict__ wv,
    __hip_bfloat16* __restrict__ wqkb, __hip_bfloat16* __restrict__ wvb)
{
    int id = blockIdx.x * 256 + threadIdx.x;
    if (id < 64*256) {
        float v = (id < 32*256) ? wq[id] : wk[id - 32*256];
        wqkb[id] = __float2bfloat16(v);
    } else {
        int j = id - 64*256;
        wvb[j] = __float2bfloat16(wv[j]);
    }
}

// ------------- K0b: x -> xbT [B][N][C] bf16 + xb [B][C][N] bf16 -------------
__global__ __launch_bounds__(256) void convert_T(
    const float* __restrict__ x, __hip_bfloat16* __restrict__ xbT,
    __hip_bfloat16* __restrict__ xb)
{
    int b = blockIdx.z, c0 = blockIdx.y * 64, n0 = blockIdx.x * 64;
    __shared__ float t[64][65];
    int tid = threadIdx.x;
    int nn = tid & 63, ch = tid >> 6;
    const float* xp = x + (size_t)b*CH*NP + (size_t)c0*NP + n0;
    #pragma unroll
    for (int u = 0; u < 16; ++u) {
        float v = xp[(size_t)(ch + u*4)*NP + nn];
        t[ch + u*4][nn] = v;
        xb[((size_t)b*CH + c0 + ch + u*4)*NP + n0 + nn] = __float2bfloat16(v);
    }
    __syncthreads();
    int n = tid >> 2, seg = tid & 3;
    union { __hip_bfloat16 h[16]; bf16x8 v[2]; } u16;
    #pragma unroll
    for (int u = 0; u < 16; ++u)
        u16.h[u] = __float2bfloat16(t[seg*16 + u][n]);
    __hip_bfloat16* dst = xbT + ((size_t)b*NP + n0 + n)*CH + c0 + seg*16;
    *(bf16x8*)dst = u16.v[0];
    *(bf16x8*)(dst + 8) = u16.v[1];
}

// -------------------- K1: q,k projections (MFMA) ----------------------------
// D[n][o] = sum_d xbT[n][d] * wqk[o][d];  o<32 -> q (scaled by log2e), else k.
__global__ __launch_bounds__(256) void qk_kernel(
    const __hip_bfloat16* __restrict__ xbT, const __hip_bfloat16* __restrict__ wqkb,
    const float* __restrict__ bq, const float* __restrict__ bk,
    __hip_bfloat16* __restrict__ qt, __hip_bfloat16* __restrict__ kt)
{
    const int b = blockIdx.y, n0 = blockIdx.x * 128;
    const int tid = threadIdx.x;
    const int w = tid >> 6, l = tid & 63, g = l >> 4, li = l & 15;

    __shared__ __align__(16) __hip_bfloat16 Ap[128*64];
    __shared__ __align__(16) __hip_bfloat16 Bp[64*64];

    f32x4 acc[2][4];
    #pragma unroll
    for (int mf = 0; mf < 2; ++mf)
        #pragma unroll
        for (int nf = 0; nf < 4; ++nf) acc[mf][nf] = (f32x4){0.f,0.f,0.f,0.f};

    const __hip_bfloat16* asrc = xbT + ((size_t)b*NP + n0)*CH;
    for (int kt4 = 0; kt4 < 4; ++kt4) {
        stage_panel64(asrc, CH, kt4*64, Ap, 128, w, l);
        stage_panel64(wqkb, CH, kt4*64, Bp, 64, w, l);
        __syncthreads();
        #pragma unroll
        for (int ks = 0; ks < 2; ++ks) {
            bf16x8 af[2], bf[4];
            #pragma unroll
            for (int mf = 0; mf < 2; ++mf) af[mf] = frag64(Ap, w*32 + mf*16 + li, ks*4 + g);
            #pragma unroll
            for (int nf = 0; nf < 4; ++nf) bf[nf] = frag64(Bp, nf*16 + li, ks*4 + g);
            #pragma unroll
            for (int mf = 0; mf < 2; ++mf)
                #pragma unroll
                for (int nf = 0; nf < 4; ++nf)
                    acc[mf][nf] = MFMA16(af[mf], bf[nf], acc[mf][nf]);
        }
        __syncthreads();
    }
    #pragma unroll
    for (int mf = 0; mf < 2; ++mf)
        #pragma unroll
        for (int nf = 0; nf < 4; ++nf)
            #pragma unroll
            for (int q = 0; q < 4; ++q) {
                int n = n0 + w*32 + mf*16 + g*4 + q;
                int o = nf*16 + li;
                float bias = (o < 32) ? bq[o] : bk[o - 32];
                float scl  = (o < 32) ? LOG2E : 1.0f;
                __hip_bfloat16* dst = (o < 32) ? qt : kt;
                dst[((size_t)b*NP + n)*C8 + (o & 31)] =
                    __float2bfloat16((acc[mf][nf][q] + bias) * scl);
            }
}

// -------------------- K2: v projection (MFMA) -> vb [B][C][N] ---------------
__global__ __launch_bounds__(256) void v_kernel(
    const __hip_bfloat16* __restrict__ xbT, const __hip_bfloat16* __restrict__ wvb,
    const float* __restrict__ bv, __hip_bfloat16* __restrict__ vb)
{
    const int b = blockIdx.y, n0 = blockIdx.x * 64;
    const int tid = threadIdx.x;
    const int w = tid >> 6, l = tid & 63, g = l >> 4, li = l & 15;

    __shared__ __align__(16) char smem[40960];
    __hip_bfloat16* Ap = (__hip_bfloat16*)smem;
    __hip_bfloat16* Bp = (__hip_bfloat16*)(smem + 32768);
    __hip_bfloat16* vt = (__hip_bfloat16*)smem;

    f32x4 acc[4][4];
    #pragma unroll
    for (int mf = 0; mf < 4; ++mf)
        #pragma unroll
        for (int nf = 0; nf < 4; ++nf) acc[mf][nf] = (f32x4){0.f,0.f,0.f,0.f};

    const __hip_bfloat16* bsrc = xbT + ((size_t)b*NP + n0)*CH;
    for (int kt4 = 0; kt4 < 4; ++kt4) {
        stage_panel64(wvb, CH, kt4*64, Ap, 256, w, l);
        stage_panel64(bsrc, CH, kt4*64, Bp, 64, w, l);
        __syncthreads();
        #pragma unroll
        for (int ks = 0; ks < 2; ++ks) {
            bf16x8 af[4], bf[4];
            #pragma unroll
            for (int mf = 0; mf < 4; ++mf) af[mf] = frag64(Ap, w*64 + mf*16 + li, ks*4 + g);
            #pragma unroll
            for (int nf = 0; nf < 4; ++nf) bf[nf] = frag64(Bp, nf*16 + li, ks*4 + g);
            #pragma unroll
            for (int mf = 0; mf < 4; ++mf)
                #pragma unroll
                for (int nf = 0; nf < 4; ++nf)
                    acc[mf][nf] = MFMA16(af[mf], bf[nf], acc[mf][nf]);
        }
        __syncthreads();
    }
    #pragma unroll
    for (int mf = 0; mf < 4; ++mf)
        #pragma unroll
        for (int nf = 0; nf < 4; ++nf)
            #pragma unroll
            for (int q = 0; q < 4; ++q) {
                int c = w*64 + mf*16 + g*4 + q;
                int n = nf*16 + li;
                vt[c*72 + n] = __float2bfloat16(acc[mf][nf][q] + bv[c]);
            }
    __syncthreads();
    for (int S = tid; S < 2048; S += 256) {
        int c = S >> 3, s = S & 7;
        bf16x8 v = *(const bf16x8*)((const char*)vt + c*144 + s*16);
        *(bf16x8*)(vb + ((size_t)b*CH + c)*NP + n0 + s*8) = v;
    }
}

// -------------------- K3: CAM energy partials (MFMA, bf16 DMA staging) ------
__global__ __launch_bounds__(256) void energy_kernel(
    const __hip_bfloat16* __restrict__ xb, float* __restrict__ E_part)
{
    const int rh = blockIdx.x, kp = blockIdx.y, b = blockIdx.z;
    const int tid = threadIdx.x;
    const int w = tid >> 6, l = tid & 63, g = l >> 4, li = l & 15;

    __shared__ __align__(16) __hip_bfloat16 P[256*64];

    f32x4 acc[16];
    #pragma unroll
    for (int nf = 0; nf < 16; ++nf) acc[nf] = (f32x4){0.f,0.f,0.f,0.f};

    const __hip_bfloat16* xp = xb + (size_t)b*CH*NP;
    for (int kt4 = 0; kt4 < 16; ++kt4) {
        int k0 = kp*1024 + kt4*64;
        stage_panel64(xp, NP, k0, P, 256, w, l);
        __syncthreads();
        #pragma unroll
        for (int ks = 0; ks < 2; ++ks) {
            bf16x8 af = frag64(P, rh*64 + w*16 + li, ks*4 + g);
            #pragma unroll
            for (int nf = 0; nf < 16; ++nf) {
                bf16x8 bf = frag64(P, nf*16 + li, ks*4 + g);
                acc[nf] = MFMA16(af, bf, acc[nf]);
            }
        }
        __syncthreads();
    }
    #pragma unroll
    for (int nf = 0; nf < 16; ++nf)
        #pragma unroll
        for (int q = 0; q < 4; ++q) {
            int r = rh*64 + w*16 + g*4 + q;
            int c = nf*16 + li;
            E_part[(((size_t)b*4 + kp)*CH + r)*CH + c] = acc[nf][q];
        }
}

// -------------------- K4: softmax over C (fused partial reduce) -> bf16 -----
__global__ __launch_bounds__(256) void cam_softmax(
    const float* __restrict__ E_part, __hip_bfloat16* __restrict__ attnb)
{
    int b = blockIdx.y, r = blockIdx.x;
    int tid = threadIdx.x;
    int lane = tid & 63, wid = tid >> 6;
    const float* base = E_part + ((size_t)b*4*CH + r)*CH + tid;
    float e = base[0] + base[CH*CH] + base[2*CH*CH] + base[3*CH*CH];

    __shared__ float redm[4], reds[4];
    float m = e;
    #pragma unroll
    for (int off = 32; off >= 1; off >>= 1) m = fmaxf(m, __shfl_xor(m, off));
    if (lane == 0) redm[wid] = m;
    __syncthreads();
    m = fmaxf(fmaxf(redm[0], redm[1]), fmaxf(redm[2], redm[3]));

    float p = __expf(e - m);
    float s = p;
    #pragma unroll
    for (int off = 32; off >= 1; off >>= 1) s += __shfl_xor(s, off);
    if (lane == 0) reds[wid] = s;
    __syncthreads();
    s = reds[0] + reds[1] + reds[2] + reds[3];
    attnb[((size_t)b*CH + r)*CH + tid] = __float2bfloat16(p / s);
}

// -------------------- K5: out = gamma*(A@X) + x (MFMA) ----------------------
__global__ __launch_bounds__(256) void apply_kernel(
    const __hip_bfloat16* __restrict__ attnb, const __hip_bfloat16* __restrict__ xbT,
    const float* __restrict__ x, const float* __restrict__ gamma,
    float* __restrict__ out)
{
    const int b = blockIdx.y, n0 = blockIdx.x * 64;
    const int tid = threadIdx.x;
    const int w = tid >> 6, l = tid & 63, g = l >> 4, li = l & 15;

    __shared__ __align__(16) __hip_bfloat16 Ap[256*64];
    __shared__ __align__(16) __hip_bfloat16 Bp[64*64];

    f32x4 acc[4][4];
    #pragma unroll
    for (int mf = 0; mf < 4; ++mf)
        #pragma unroll
        for (int nf = 0; nf < 4; ++nf) acc[mf][nf] = (f32x4){0.f,0.f,0.f,0.f};

    const __hip_bfloat16* asrc = attnb + (size_t)b*CH*CH;
    const __hip_bfloat16* bsrc = xbT + ((size_t)b*NP + n0)*CH;
    for (int kt4 = 0; kt4 < 4; ++kt4) {
        stage_panel64(asrc, CH, kt4*64, Ap, 256, w, l);
        stage_panel64(bsrc, CH, kt4*64, Bp, 64, w, l);
        __syncthreads();
        #pragma unroll
        for (int ks = 0; ks < 2; ++ks) {
            bf16x8 af[4], bf[4];
            #pragma unroll
            for (int mf = 0; mf < 4; ++mf) af[mf] = frag64(Ap, w*64 + mf*16 + li, ks*4 + g);
            #pragma unroll
            for (int nf = 0; nf < 4; ++nf) bf[nf] = frag64(Bp, nf*16 + li, ks*4 + g);
            #pragma unroll
            for (int mf = 0; mf < 4; ++mf)
                #pragma unroll
                for (int nf = 0; nf < 4; ++nf)
                    acc[mf][nf] = MFMA16(af[mf], bf[nf], acc[mf][nf]);
        }
        __syncthreads();
    }
    float g0 = gamma[0];
    #pragma unroll
    for (int mf = 0; mf < 4; ++mf)
        #pragma unroll
        for (int nf = 0; nf < 4; ++nf)
            #pragma unroll
            for (int q = 0; q < 4; ++q) {
                int c = w*64 + mf*16 + g*4 + q;
                int n = n0 + nf*16 + li;
                size_t idx = ((size_t)b*CH + c)*NP + n;
                out[idx] = g0*acc[mf][nf][q] + x[idx];
            }
}

// ---- K6: PAM flash v9 — 32x32 MFMA, permlane P-exchange, 1 barrier/iter ----
// 4 waves = (ih: i-half of 64-tile) x (ch: c-half). QK^T (32x32x16, K as A)
// makes P lane-local in i; 2x v_permlane32_swap per k-chunk builds PV A-frags
// in-register (no ps LDS). V in shared dbuf LDS, own-vmcnt(4) before the
// single barrier (K's 4 reg loads are the 4 newest VMEM ops, clamped at tail).
__global__ __launch_bounds__(256, 2) void pam_flash(
    const __hip_bfloat16* __restrict__ qg,   // [B][N][32] (pre-scaled)
    const __hip_bfloat16* __restrict__ kg,   // [B][N][32]
    const __hip_bfloat16* __restrict__ vg,   // [B][C][N]
    float* __restrict__ out)
{
    const int bid = blockIdx.x;
    const int b   = bid & 7;                 // batch -> XCD pin
    const int i0  = (bid >> 3) * 64;
    const int tid = threadIdx.x;
    const int w   = tid >> 6;                // 0..3
    const int ih  = w >> 1;                  // i-half (32 rows)
    const int ch  = w & 1;                   // c-half (128 channels)
    const int l   = tid & 63;
    const int l31 = l & 31;
    const int hh  = l >> 5;

    __shared__ __align__(16) __hip_bfloat16 vsb[2][256*64];  // 64KB V dbuf
    __shared__ float lsh[64];

    // ---- V staging: slot S16 = w*512 + it*64 + l; c = w*64 + it*8 + (l>>3)
    // stored data chunk = (l&7) ^ key(c), key(c) = (c ^ (c>>3)) & 7
    const char* vsrc[8];
    #pragma unroll
    for (int it = 0; it < 8; ++it) {
        int c  = w*64 + it*8 + (l >> 3);
        int jb = (l & 7) ^ (l >> 3) ^ it;
        vsrc[it] = (const char*)vg + ((size_t)(b*CH + c)*NP + jb*8)*2;
    }

#define ISSUE_V(JT, BUF)                                                      \
    { _Pragma("unroll")                                                       \
      for (int it = 0; it < 8; ++it)                                          \
          async_copy16(vsrc[it] + (size_t)(JT)*128,                           \
                       (char*)vsb[BUF] + w*8192 + it*1024); }

    // ---- K A-frags (32x32x16): row j = l31, k d = hh*8+e; 2 jsub x 2 dk ----
    const char* kbase = (const char*)kg + (size_t)b*NP*64 + l31*64 + hh*16;
#define LOADK(DST, JT)                                                        \
    { _Pragma("unroll")                                                       \
      for (int js = 0; js < 2; ++js)                                          \
          _Pragma("unroll")                                                   \
          for (int dk = 0; dk < 2; ++dk)                                      \
              DST[js][dk] = *(const bf16x8*)(kbase +                          \
                  ((size_t)(JT)*64 + js*32)*64 + dk*32); }

    // ---- prologue: V(0) first (oldest), then K(0),K(1),Q ----
    ISSUE_V(0, 0);
    SBAR();
    bf16x8 kA[2][2], kB[2][2];
    LOADK(kA, 0);
    LOADK(kB, 1);
    const char* qbase = (const char*)qg + ((size_t)b*NP + i0 + ih*32 + l31)*64 + hh*16;
    bf16x8 qf[2];
    qf[0] = *(const bf16x8*)(qbase);
    qf[1] = *(const bf16x8*)(qbase + 32);
    SBAR();

    f32x16 acc[4];
    #pragma unroll
    for (int ci = 0; ci < 4; ++ci) acc[ci] = zero16();
    float lacc = 0.f;

#define PAM_STEP(JT, KSET, BUF)                                               \
    {                                                                         \
        bf16x8 paf[4];                                                        \
        _Pragma("unroll")                                                     \
        for (int js = 0; js < 2; ++js) {                                      \
            f32x16 st = zero16();                                             \
            st = MFMA32(KSET[js][0], qf[0], st);                              \
            st = MFMA32(KSET[js][1], qf[1], st);                              \
            unsigned W[4][2];                                                 \
            _Pragma("unroll")                                                 \
            for (int q = 0; q < 4; ++q) {                                     \
                float p0 = EXP2(st[4*q+0]);                                   \
                float p1 = EXP2(st[4*q+1]);                                   \
                float p2 = EXP2(st[4*q+2]);                                   \
                float p3 = EXP2(st[4*q+3]);                                   \
                lacc += (p0 + p1) + (p2 + p3);                                \
                W[q][0] = pk2(p0, p1);                                        \
                W[q][1] = pk2(p2, p3);                                        \
            }                                                                 \
            plswap(W[0][0], W[1][0]);                                         \
            plswap(W[0][1], W[1][1]);                                         \
            plswap(W[2][0], W[3][0]);                                         \
            plswap(W[2][1], W[3][1]);                                         \
            union { unsigned u[4]; bf16x8 v; } f0, f1;                        \
            f0.u[0] = W[0][0]; f0.u[1] = W[0][1];                             \
            f0.u[2] = W[1][0]; f0.u[3] = W[1][1];                             \
            f1.u[0] = W[2][0]; f1.u[1] = W[2][1];                             \
            f1.u[2] = W[3][0]; f1.u[3] = W[3][1];                             \
            paf[js*2 + 0] = f0.v;                                             \
            paf[js*2 + 1] = f1.v;                                             \
        }                                                                     \
        asm volatile("s_waitcnt vmcnt(4)" ::: "memory");                      \
        SBAR();                                                               \
        __builtin_amdgcn_s_barrier();                                         \
        SBAR();                                                               \
        if ((JT) < 63) { ISSUE_V((JT) + 1, (BUF) ^ 1); }                      \
        SBAR();                                                               \
        LOADK(KSET, ((JT) + 2 < 64) ? (JT) + 2 : 63);                         \
        SBAR();                                                               \
        __builtin_amdgcn_s_setprio(1);                                        \
        {                                                                     \
            const char* vbp = (const char*)vsb[BUF];                          \
            _Pragma("unroll")                                                 \
            for (int ci = 0; ci < 4; ++ci) {                                  \
                int c = ch*128 + ci*32 + l31;                                 \
                int key = (l & 7) ^ ((ci*4 + (l31 >> 3)) & 7);                \
                _Pragma("unroll")                                             \
                for (int kc = 0; kc < 4; ++kc) {                              \
                    bf16x8 bv = *(const bf16x8*)(vbp + c*128 +                \
                                    (((2*kc + hh) ^ key) << 4));              \
                    acc[ci] = MFMA32(paf[kc], bv, acc[ci]);                   \
                }                                                             \
            }                                                                 \
        }                                                                     \
        __builtin_amdgcn_s_setprio(0);                                        \
        SBAR();                                                               \
    }

    for (int jt = 0; jt < 64; jt += 2) {
        PAM_STEP(jt,     kA, 0);
        PAM_STEP(jt + 1, kB, 1);
    }

    // ---- l totals: lanes l and l^32 share i; both halves end identical ----
    lacc += __shfl_xor(lacc, 32);
    lsh[ih*32 + l31] = lacc;       // duplicate writers write identical values
    __syncthreads();

    float linv[4][4];
    #pragma unroll
    for (int rq = 0; rq < 4; ++rq)
        #pragma unroll
        for (int e = 0; e < 4; ++e)
            linv[rq][e] = 1.0f / lsh[ih*32 + 8*rq + 4*hh + e];

    #pragma unroll
    for (int ci = 0; ci < 4; ++ci) {
        int c = ch*128 + ci*32 + l31;
        size_t rowbase = ((size_t)b*CH + c)*NP + i0 + ih*32;
        #pragma unroll
        for (int rq = 0; rq < 4; ++rq) {
            size_t idx = rowbase + 8*rq + 4*hh;
            float4 o = *(float4*)(out + idx);
            o.x += acc[ci][4*rq+0]*linv[rq][0];
            o.y += acc[ci][4*rq+1]*linv[rq][1];
            o.z += acc[ci][4*rq+2]*linv[rq][2];
            o.w += acc[ci][4*rq+3]*linv[rq][3];
            *(float4*)(out + idx) = o;
        }
    }
#undef PAM_STEP
#undef ISSUE_V
#undef LOADK
}

// ---------------------------------------------------------------------------
extern "C" void kernel_launch(void* const* d_in, const int* in_sizes, int n_in,
                              void* d_out, int out_size, void* d_ws, size_t ws_size,
                              hipStream_t stream)
{
    const float* x     = (const float*)d_in[0];
    const float* gamma = (const float*)d_in[1];
    const float* wq    = (const float*)d_in[2];
    const float* bq    = (const float*)d_in[3];
    const float* wk    = (const float*)d_in[4];
    const float* bk    = (const float*)d_in[5];
    const float* wv    = (const float*)d_in[6];
    const float* bv    = (const float*)d_in[7];
    float* out = (float*)d_out;

    char* ws = (char*)d_ws;
    __hip_bfloat16* xbT   = (__hip_bfloat16*)ws;                 ws += (size_t)BB*NP*CH*2;
    __hip_bfloat16* xb    = (__hip_bfloat16*)ws;                 ws += (size_t)BB*CH*NP*2;
    __hip_bfloat16* qtb   = (__hip_bfloat16*)ws;                 ws += (size_t)BB*NP*C8*2;
    __hip_bfloat16* ktb   = (__hip_bfloat16*)ws;                 ws += (size_t)BB*NP*C8*2;
    __hip_bfloat16* vbb   = (__hip_bfloat16*)ws;                 ws += (size_t)BB*CH*NP*2;
    __hip_bfloat16* wqkb  = (__hip_bfloat16*)ws;                 ws += 64*CH*2;
    __hip_bfloat16* wvb   = (__hip_bfloat16*)ws;                 ws += CH*CH*2;
    float*          Epart = (float*)ws;                          ws += (size_t)BB*4*CH*CH*4;
    __hip_bfloat16* attnb = (__hip_bfloat16*)ws;                 ws += (size_t)BB*CH*CH*2;

    convert_w    <<<dim3(320),        256, 0, stream>>>(wq, wk, wv, wqkb, wvb);
    convert_T    <<<dim3(64, 4, BB),  256, 0, stream>>>(x, xbT, xb);
    qk_kernel    <<<dim3(32, BB),     256, 0, stream>>>(xbT, wqkb, bq, bk, qtb, ktb);
    v_kernel     <<<dim3(64, BB),     256, 0, stream>>>(xbT, wvb, bv, vbb);
    energy_kernel<<<dim3(4, 4, BB),   256, 0, stream>>>(xb, Epart);
    cam_softmax  <<<dim3(CH, BB),     256, 0, stream>>>(Epart, attnb);
    apply_kernel <<<dim3(64, BB),     256, 0, stream>>>(attnb, xbT, x, gamma, out);
    pam_flash    <<<dim3(512),        256, 0, stream>>>(qtb, ktb, vbb, out);
}

// Round 10
// 179.595 us; speedup vs baseline: 1.3113x; 1.1429x over previous
//
#include <hip/hip_runtime.h>
#include <hip/hip_bf16.h>

#define BB 8
#define CH 256
#define C8 32
#define NP 4096   // 64*64

typedef __attribute__((ext_vector_type(8))) short bf16x8;
typedef __attribute__((ext_vector_type(4))) float f32x4;

#define MFMA16(a, b, c) __builtin_amdgcn_mfma_f32_16x16x32_bf16(a, b, c, 0, 0, 0)
#define SBAR() __builtin_amdgcn_sched_barrier(0)

#if __has_builtin(__builtin_amdgcn_exp2f)
#define EXP2(x) __builtin_amdgcn_exp2f(x)
#else
#define EXP2(x) exp2f(x)
#endif

#define LOG2E 1.44269504088896340736f

__device__ __forceinline__ void async_copy16(const void* src, void* dst_lds) {
    __builtin_amdgcn_global_load_lds(
        (const __attribute__((address_space(1))) unsigned int*)src,
        (__attribute__((address_space(3))) unsigned int*)dst_lds, 16, 0, 0);
}

__device__ __forceinline__ unsigned long long pack4bf(float a, float b, float c, float d) {
    union { __hip_bfloat16 h[4]; unsigned long long u; } p;
    p.h[0] = __float2bfloat16(a);
    p.h[1] = __float2bfloat16(b);
    p.h[2] = __float2bfloat16(c);
    p.h[3] = __float2bfloat16(d);
    return p.u;
}

// Stage a [nrows][64] bf16 LDS panel (128B rows, XOR-swizzled: data k-chunk t
// of row r lives at slot t^(r&7)) from row-major bf16 global.
__device__ __forceinline__ void stage_panel64(
    const __hip_bfloat16* __restrict__ src, int rowStride, int k0,
    __hip_bfloat16* lds, int nrows, int w, int l)
{
    const int nslots = nrows * 8;
    for (int S0 = w*64; S0 < nslots; S0 += 256) {
        int S = S0 + l;
        int r = S >> 3, s = S & 7;
        int jb = s ^ (r & 7);
        async_copy16(src + (size_t)r*rowStride + k0 + jb*8,
                     (char*)lds + (size_t)S0*16);
    }
}

__device__ __forceinline__ bf16x8 frag64(const __hip_bfloat16* lds, int r, int t) {
    return *(const bf16x8*)((const char*)lds + r*128 + ((t ^ (r & 7)) << 4));
}

// ------- K0: x -> xbT [B][N][C] bf16 + xb [B][C][N] bf16 (+ weights) --------
__global__ __launch_bounds__(256) void convert_T(
    const float* __restrict__ x, __hip_bfloat16* __restrict__ xbT,
    __hip_bfloat16* __restrict__ xb,
    const float* __restrict__ wq, const float* __restrict__ wk,
    const float* __restrict__ wv,
    __hip_bfloat16* __restrict__ wqkb, __hip_bfloat16* __restrict__ wvb)
{
    int b = blockIdx.z, c0 = blockIdx.y * 64, n0 = blockIdx.x * 64;
    __shared__ float t[64][65];
    int tid = threadIdx.x;

    // side work on the 256 b==0 blocks: weights -> bf16 (320 elems each)
    if (b == 0) {
        int wid = blockIdx.y * 64 + blockIdx.x;
        #pragma unroll
        for (int e = 0; e < 2; ++e) {
            int id = wid*320 + e*256 + tid;
            if (e*256 + tid < 320) {
                if (id < 64*256) {
                    float v = (id < 32*256) ? wq[id] : wk[id - 32*256];
                    wqkb[id] = __float2bfloat16(v);
                } else {
                    int j = id - 64*256;
                    wvb[j] = __float2bfloat16(wv[j]);
                }
            }
        }
    }

    int nn = tid & 63, ch = tid >> 6;
    const float* xp = x + (size_t)b*CH*NP + (size_t)c0*NP + n0;
    #pragma unroll
    for (int u = 0; u < 16; ++u) {
        float v = xp[(size_t)(ch + u*4)*NP + nn];
        t[ch + u*4][nn] = v;
        xb[((size_t)b*CH + c0 + ch + u*4)*NP + n0 + nn] = __float2bfloat16(v);
    }
    __syncthreads();
    int n = tid >> 2, seg = tid & 3;
    union { __hip_bfloat16 h[16]; bf16x8 v[2]; } u16;
    #pragma unroll
    for (int u = 0; u < 16; ++u)
        u16.h[u] = __float2bfloat16(t[seg*16 + u][n]);
    __hip_bfloat16* dst = xbT + ((size_t)b*NP + n0 + n)*CH + c0 + seg*16;
    *(bf16x8*)dst = u16.v[0];
    *(bf16x8*)(dst + 8) = u16.v[1];
}

// -------------------- K1: q,k projections (MFMA) ----------------------------
// D[n][o] = sum_d xbT[n][d] * wqk[o][d];  o<32 -> q (scaled by log2e), else k.
__global__ __launch_bounds__(256) void qk_kernel(
    const __hip_bfloat16* __restrict__ xbT, const __hip_bfloat16* __restrict__ wqkb,
    const float* __restrict__ bq, const float* __restrict__ bk,
    __hip_bfloat16* __restrict__ qt, __hip_bfloat16* __restrict__ kt)
{
    const int b = blockIdx.y, n0 = blockIdx.x * 128;
    const int tid = threadIdx.x;
    const int w = tid >> 6, l = tid & 63, g = l >> 4, li = l & 15;

    __shared__ __align__(16) __hip_bfloat16 Ap[128*64];
    __shared__ __align__(16) __hip_bfloat16 Bp[64*64];

    f32x4 acc[2][4];
    #pragma unroll
    for (int mf = 0; mf < 2; ++mf)
        #pragma unroll
        for (int nf = 0; nf < 4; ++nf) acc[mf][nf] = (f32x4){0.f,0.f,0.f,0.f};

    const __hip_bfloat16* asrc = xbT + ((size_t)b*NP + n0)*CH;
    for (int kt4 = 0; kt4 < 4; ++kt4) {
        stage_panel64(asrc, CH, kt4*64, Ap, 128, w, l);
        stage_panel64(wqkb, CH, kt4*64, Bp, 64, w, l);
        __syncthreads();
        #pragma unroll
        for (int ks = 0; ks < 2; ++ks) {
            bf16x8 af[2], bf[4];
            #pragma unroll
            for (int mf = 0; mf < 2; ++mf) af[mf] = frag64(Ap, w*32 + mf*16 + li, ks*4 + g);
            #pragma unroll
            for (int nf = 0; nf < 4; ++nf) bf[nf] = frag64(Bp, nf*16 + li, ks*4 + g);
            #pragma unroll
            for (int mf = 0; mf < 2; ++mf)
                #pragma unroll
                for (int nf = 0; nf < 4; ++nf)
                    acc[mf][nf] = MFMA16(af[mf], bf[nf], acc[mf][nf]);
        }
        __syncthreads();
    }
    #pragma unroll
    for (int mf = 0; mf < 2; ++mf)
        #pragma unroll
        for (int nf = 0; nf < 4; ++nf)
            #pragma unroll
            for (int q = 0; q < 4; ++q) {
                int n = n0 + w*32 + mf*16 + g*4 + q;
                int o = nf*16 + li;
                float bias = (o < 32) ? bq[o] : bk[o - 32];
                float scl  = (o < 32) ? LOG2E : 1.0f;
                __hip_bfloat16* dst = (o < 32) ? qt : kt;
                dst[((size_t)b*NP + n)*C8 + (o & 31)] =
                    __float2bfloat16((acc[mf][nf][q] + bias) * scl);
            }
}

// -------------------- K2: v projection (MFMA) -> vb [B][C][N] ---------------
__global__ __launch_bounds__(256) void v_kernel(
    const __hip_bfloat16* __restrict__ xbT, const __hip_bfloat16* __restrict__ wvb,
    const float* __restrict__ bv, __hip_bfloat16* __restrict__ vb)
{
    const int b = blockIdx.y, n0 = blockIdx.x * 64;
    const int tid = threadIdx.x;
    const int w = tid >> 6, l = tid & 63, g = l >> 4, li = l & 15;

    __shared__ __align__(16) char smem[40960];
    __hip_bfloat16* Ap = (__hip_bfloat16*)smem;
    __hip_bfloat16* Bp = (__hip_bfloat16*)(smem + 32768);
    __hip_bfloat16* vt = (__hip_bfloat16*)smem;

    f32x4 acc[4][4];
    #pragma unroll
    for (int mf = 0; mf < 4; ++mf)
        #pragma unroll
        for (int nf = 0; nf < 4; ++nf) acc[mf][nf] = (f32x4){0.f,0.f,0.f,0.f};

    const __hip_bfloat16* bsrc = xbT + ((size_t)b*NP + n0)*CH;
    for (int kt4 = 0; kt4 < 4; ++kt4) {
        stage_panel64(wvb, CH, kt4*64, Ap, 256, w, l);
        stage_panel64(bsrc, CH, kt4*64, Bp, 64, w, l);
        __syncthreads();
        #pragma unroll
        for (int ks = 0; ks < 2; ++ks) {
            bf16x8 af[4], bf[4];
            #pragma unroll
            for (int mf = 0; mf < 4; ++mf) af[mf] = frag64(Ap, w*64 + mf*16 + li, ks*4 + g);
            #pragma unroll
            for (int nf = 0; nf < 4; ++nf) bf[nf] = frag64(Bp, nf*16 + li, ks*4 + g);
            #pragma unroll
            for (int mf = 0; mf < 4; ++mf)
                #pragma unroll
                for (int nf = 0; nf < 4; ++nf)
                    acc[mf][nf] = MFMA16(af[mf], bf[nf], acc[mf][nf]);
        }
        __syncthreads();
    }
    #pragma unroll
    for (int mf = 0; mf < 4; ++mf)
        #pragma unroll
        for (int nf = 0; nf < 4; ++nf)
            #pragma unroll
            for (int q = 0; q < 4; ++q) {
                int c = w*64 + mf*16 + g*4 + q;
                int n = nf*16 + li;
                vt[c*72 + n] = __float2bfloat16(acc[mf][nf][q] + bv[c]);
            }
    __syncthreads();
    for (int S = tid; S < 2048; S += 256) {
        int c = S >> 3, s = S & 7;
        bf16x8 v = *(const bf16x8*)((const char*)vt + c*144 + s*16);
        *(bf16x8*)(vb + ((size_t)b*CH + c)*NP + n0 + s*8) = v;
    }
}

// -------------------- K3: CAM energy partials (MFMA, bf16 DMA staging) ------
__global__ __launch_bounds__(256) void energy_kernel(
    const __hip_bfloat16* __restrict__ xb, float* __restrict__ E_part)
{
    const int rh = blockIdx.x, kp = blockIdx.y, b = blockIdx.z;
    const int tid = threadIdx.x;
    const int w = tid >> 6, l = tid & 63, g = l >> 4, li = l & 15;

    __shared__ __align__(16) __hip_bfloat16 P[256*64];

    f32x4 acc[16];
    #pragma unroll
    for (int nf = 0; nf < 16; ++nf) acc[nf] = (f32x4){0.f,0.f,0.f,0.f};

    const __hip_bfloat16* xp = xb + (size_t)b*CH*NP;
    for (int kt4 = 0; kt4 < 16; ++kt4) {
        int k0 = kp*1024 + kt4*64;
        stage_panel64(xp, NP, k0, P, 256, w, l);
        __syncthreads();
        #pragma unroll
        for (int ks = 0; ks < 2; ++ks) {
            bf16x8 af = frag64(P, rh*64 + w*16 + li, ks*4 + g);
            #pragma unroll
            for (int nf = 0; nf < 16; ++nf) {
                bf16x8 bf = frag64(P, nf*16 + li, ks*4 + g);
                acc[nf] = MFMA16(af, bf, acc[nf]);
            }
        }
        __syncthreads();
    }
    #pragma unroll
    for (int nf = 0; nf < 16; ++nf)
        #pragma unroll
        for (int q = 0; q < 4; ++q) {
            int r = rh*64 + w*16 + g*4 + q;
            int c = nf*16 + li;
            E_part[(((size_t)b*4 + kp)*CH + r)*CH + c] = acc[nf][q];
        }
}

// -------------------- K4: softmax over C (fused partial reduce) -> bf16 -----
__global__ __launch_bounds__(256) void cam_softmax(
    const float* __restrict__ E_part, __hip_bfloat16* __restrict__ attnb)
{
    int b = blockIdx.y, r = blockIdx.x;
    int tid = threadIdx.x;
    int lane = tid & 63, wid = tid >> 6;
    const float* base = E_part + ((size_t)b*4*CH + r)*CH + tid;
    float e = base[0] + base[CH*CH] + base[2*CH*CH] + base[3*CH*CH];

    __shared__ float redm[4], reds[4];
    float m = e;
    #pragma unroll
    for (int off = 32; off >= 1; off >>= 1) m = fmaxf(m, __shfl_xor(m, off));
    if (lane == 0) redm[wid] = m;
    __syncthreads();
    m = fmaxf(fmaxf(redm[0], redm[1]), fmaxf(redm[2], redm[3]));

    float p = __expf(e - m);
    float s = p;
    #pragma unroll
    for (int off = 32; off >= 1; off >>= 1) s += __shfl_xor(s, off);
    if (lane == 0) reds[wid] = s;
    __syncthreads();
    s = reds[0] + reds[1] + reds[2] + reds[3];
    attnb[((size_t)b*CH + r)*CH + tid] = __float2bfloat16(p / s);
}

// -------------------- K5: out = gamma*(A@X) + x (MFMA) ----------------------
__global__ __launch_bounds__(256) void apply_kernel(
    const __hip_bfloat16* __restrict__ attnb, const __hip_bfloat16* __restrict__ xbT,
    const float* __restrict__ x, const float* __restrict__ gamma,
    float* __restrict__ out)
{
    const int b = blockIdx.y, n0 = blockIdx.x * 64;
    const int tid = threadIdx.x;
    const int w = tid >> 6, l = tid & 63, g = l >> 4, li = l & 15;

    __shared__ __align__(16) __hip_bfloat16 Ap[256*64];
    __shared__ __align__(16) __hip_bfloat16 Bp[64*64];

    f32x4 acc[4][4];
    #pragma unroll
    for (int mf = 0; mf < 4; ++mf)
        #pragma unroll
        for (int nf = 0; nf < 4; ++nf) acc[mf][nf] = (f32x4){0.f,0.f,0.f,0.f};

    const __hip_bfloat16* asrc = attnb + (size_t)b*CH*CH;
    const __hip_bfloat16* bsrc = xbT + ((size_t)b*NP + n0)*CH;
    for (int kt4 = 0; kt4 < 4; ++kt4) {
        stage_panel64(asrc, CH, kt4*64, Ap, 256, w, l);
        stage_panel64(bsrc, CH, kt4*64, Bp, 64, w, l);
        __syncthreads();
        #pragma unroll
        for (int ks = 0; ks < 2; ++ks) {
            bf16x8 af[4], bf[4];
            #pragma unroll
            for (int mf = 0; mf < 4; ++mf) af[mf] = frag64(Ap, w*64 + mf*16 + li, ks*4 + g);
            #pragma unroll
            for (int nf = 0; nf < 4; ++nf) bf[nf] = frag64(Bp, nf*16 + li, ks*4 + g);
            #pragma unroll
            for (int mf = 0; mf < 4; ++mf)
                #pragma unroll
                for (int nf = 0; nf < 4; ++nf)
                    acc[mf][nf] = MFMA16(af[mf], bf[nf], acc[mf][nf]);
        }
        __syncthreads();
    }
    float g0 = gamma[0];
    #pragma unroll
    for (int mf = 0; mf < 4; ++mf)
        #pragma unroll
        for (int nf = 0; nf < 4; ++nf)
            #pragma unroll
            for (int q = 0; q < 4; ++q) {
                int c = w*64 + mf*16 + g*4 + q;
                int n = n0 + nf*16 + li;
                size_t idx = ((size_t)b*CH + c)*NP + n;
                out[idx] = g0*acc[mf][nf][q] + x[idx];
            }
}

// ---- K6: PAM flash v10 — v6 schedule, ps dbuf (1 barrier/iter), V single ---
// V staging is wave-private (each wave stages+reads its own c-quarter), so the
// only cross-wave object is ps. ps double-buffer removes the 2nd barrier:
// BAR(jt+1) separates all PV(jt) reads from all B(jt+2) writes of ps[cur].
__global__ __launch_bounds__(256, 2) void pam_flash(
    const __hip_bfloat16* __restrict__ qg,   // [B][N][32] (pre-scaled)
    const __hip_bfloat16* __restrict__ kg,   // [B][N][32]
    const __hip_bfloat16* __restrict__ vg,   // [B][C][N]
    float* __restrict__ out)
{
    const int bid = blockIdx.x;
    const int b   = bid & 7;                 // batch -> XCD pin (L2 residency)
    const int i0  = (bid >> 3) * 64;
    const int tid = threadIdx.x;
    const int w   = tid >> 6;
    const int l   = tid & 63;
    const int g   = l >> 4;
    const int li  = l & 15;

    __shared__ __align__(16) __hip_bfloat16 vs[256*64];     // 32KB single, wave-private
    __shared__ __align__(16) __hip_bfloat16 ps[2][64*64];   // 16KB dbuf
    __shared__ float lsh[4][64];                            // 1KB

    // V staging geometry: slot S16 = w*512 + it*64 + l;
    // c = w*64 + it*8 + (l>>3); jb = (l&7)^(c&7) is constant across it.
    const int c0l = (w*512 + l) >> 3;
    const int jb  = (l & 7) ^ (c0l & 7);
    const char* vbase = (const char*)vg + ((size_t)(b*CH + c0l)*NP + jb*8)*2;

    // Q frags direct from global
    const char* qbase = (const char*)(qg + ((size_t)b*NP + i0)*C8);
    bf16x8 qf[4];
    #pragma unroll
    for (int t = 0; t < 4; ++t)
        qf[t] = *(const bf16x8*)(qbase + (t*16 + li)*64 + g*16);

    // K value pipeline + prologue issues (order pinned: K0, V0x8, K1)
    const char* kptr = (const char*)(kg + (size_t)b*NP*C8) + (w*16 + li)*64 + g*16;
    bf16x8 kcur = *(const bf16x8*)(kptr);
    SBAR();
    #pragma unroll
    for (int it = 0; it < 8; ++it)
        async_copy16(vbase + (size_t)it*(8*NP*2), (char*)vs + w*8192 + it*1024);
    SBAR();
    bf16x8 knext = *(const bf16x8*)(kptr + 4096);
    SBAR();

    f32x4 acc[4][4];
    #pragma unroll
    for (int t = 0; t < 4; ++t)
        #pragma unroll
        for (int ct = 0; ct < 4; ++ct)
            acc[t][ct] = (f32x4){0.f, 0.f, 0.f, 0.f};
    float lacc[4] = {0.f, 0.f, 0.f, 0.f};

    for (int jt = 0; jt < 64; ++jt) {
        const int cur = jt & 1;
        char* psc = (char*)ps + cur*8192;

        // ---- B: QK^T + exp2 + ps[cur] write ----
        f32x4 st[4];
        #pragma unroll
        for (int t = 0; t < 4; ++t) {
            f32x4 z = (f32x4){0.f, 0.f, 0.f, 0.f};
            st[t] = MFMA16(kcur, qf[t], z);
        }
        #pragma unroll
        for (int t = 0; t < 4; ++t) {
            float p0 = EXP2(st[t][0]);
            float p1 = EXP2(st[t][1]);
            float p2 = EXP2(st[t][2]);
            float p3 = EXP2(st[t][3]);
            lacc[t] += (p0 + p1) + (p2 + p3);
            *(unsigned long long*)(psc + (t*16 + li)*128 +
                (((2*w + (g >> 1)) ^ (li & 7)) << 4) + ((g & 1) << 3))
                = pack4bf(p0, p1, p2, p3);
        }
        asm volatile("s_waitcnt lgkmcnt(0)" ::: "memory");
        SBAR();
        __builtin_amdgcn_s_barrier();    // the ONLY barrier per iter
        SBAR();

        // ---- C: wait own V DMAs (K prefetch stays in flight), then PV ----
        asm volatile("s_waitcnt vmcnt(1)" ::: "memory");
        SBAR();
        __builtin_amdgcn_s_setprio(1);
        #pragma unroll
        for (int ks = 0; ks < 2; ++ks) {
            bf16x8 ap[4];
            #pragma unroll
            for (int t = 0; t < 4; ++t)
                ap[t] = *(const bf16x8*)(psc + (t*16 + li)*128 +
                            (((ks*4 + g) ^ (li & 7)) << 4));
            #pragma unroll
            for (int ct = 0; ct < 4; ++ct) {
                int c = w*64 + ct*16 + li;
                bf16x8 bv = *(const bf16x8*)((const char*)vs + c*128 +
                                (((ks*4 + g) ^ (c & 7)) << 4));
                #pragma unroll
                for (int t = 0; t < 4; ++t)
                    acc[t][ct] = MFMA16(ap[t], bv, acc[t][ct]);
            }
        }
        __builtin_amdgcn_s_setprio(0);
        SBAR();

        // ---- D: rotate K, issue V(jt+1) into SAME buffer (own reads done),
        //         K(jt+2) load (order pinned). No barrier needed. ----
        kcur = knext;
        if (jt < 63) {
            const char* vsrc_j = vbase + (size_t)(jt + 1)*128;
            #pragma unroll
            for (int it = 0; it < 8; ++it)
                async_copy16(vsrc_j + (size_t)it*(8*NP*2),
                             (char*)vs + w*8192 + it*1024);
            SBAR();
            int kn2 = (jt + 2 < 64) ? (jt + 2) : 63;
            knext = *(const bf16x8*)(kptr + (size_t)kn2*4096);
            SBAR();
        }
    }

    // ---- reduce l across lane groups then waves ----
    #pragma unroll
    for (int t = 0; t < 4; ++t) {
        float v = lacc[t];
        v += __shfl_xor(v, 16);
        v += __shfl_xor(v, 32);
        lacc[t] = v;
    }
    if (g == 0) {
        #pragma unroll
        for (int t = 0; t < 4; ++t) lsh[w][t*16 + li] = lacc[t];
    }
    __syncthreads();

    #pragma unroll
    for (int t = 0; t < 4; ++t) {
        float linv[4];
        #pragma unroll
        for (int r = 0; r < 4; ++r) {
            int il = t*16 + g*4 + r;
            linv[r] = 1.0f / (lsh[0][il] + lsh[1][il] + lsh[2][il] + lsh[3][il]);
        }
        #pragma unroll
        for (int ct = 0; ct < 4; ++ct) {
            int c = w*64 + ct*16 + li;
            size_t base = ((size_t)b*CH + c)*NP + i0 + t*16 + g*4;
            float4 o = *(float4*)(out + base);
            o.x += acc[t][ct][0]*linv[0];
            o.y += acc[t][ct][1]*linv[1];
            o.z += acc[t][ct][2]*linv[2];
            o.w += acc[t][ct][3]*linv[3];
            *(float4*)(out + base) = o;
        }
    }
}

// ---------------------------------------------------------------------------
extern "C" void kernel_launch(void* const* d_in, const int* in_sizes, int n_in,
                              void* d_out, int out_size, void* d_ws, size_t ws_size,
                              hipStream_t stream)
{
    const float* x     = (const float*)d_in[0];
    const float* gamma = (const float*)d_in[1];
    const float* wq    = (const float*)d_in[2];
    const float* bq    = (const float*)d_in[3];
    const float* wk    = (const float*)d_in[4];
    const float* bk    = (const float*)d_in[5];
    const float* wv    = (const float*)d_in[6];
    const float* bv    = (const float*)d_in[7];
    float* out = (float*)d_out;

    char* ws = (char*)d_ws;
    __hip_bfloat16* xbT   = (__hip_bfloat16*)ws;                 ws += (size_t)BB*NP*CH*2;
    __hip_bfloat16* xb    = (__hip_bfloat16*)ws;                 ws += (size_t)BB*CH*NP*2;
    __hip_bfloat16* qtb   = (__hip_bfloat16*)ws;                 ws += (size_t)BB*NP*C8*2;
    __hip_bfloat16* ktb   = (__hip_bfloat16*)ws;                 ws += (size_t)BB*NP*C8*2;
    __hip_bfloat16* vbb   = (__hip_bfloat16*)ws;                 ws += (size_t)BB*CH*NP*2;
    __hip_bfloat16* wqkb  = (__hip_bfloat16*)ws;                 ws += 64*CH*2;
    __hip_bfloat16* wvb   = (__hip_bfloat16*)ws;                 ws += CH*CH*2;
    float*          Epart = (float*)ws;                          ws += (size_t)BB*4*CH*CH*4;
    __hip_bfloat16* attnb = (__hip_bfloat16*)ws;                 ws += (size_t)BB*CH*CH*2;

    convert_T    <<<dim3(64, 4, BB),  256, 0, stream>>>(x, xbT, xb, wq, wk, wv, wqkb, wvb);
    qk_kernel    <<<dim3(32, BB),     256, 0, stream>>>(xbT, wqkb, bq, bk, qtb, ktb);
    v_kernel     <<<dim3(64, BB),     256, 0, stream>>>(xbT, wvb, bv, vbb);
    energy_kernel<<<dim3(4, 4, BB),   256, 0, stream>>>(xb, Epart);
    cam_softmax  <<<dim3(CH, BB),     256, 0, stream>>>(Epart, attnb);
    apply_kernel <<<dim3(64, BB),     256, 0, stream>>>(attnb, xbT, x, gamma, out);
    pam_flash    <<<dim3(512),        256, 0, stream>>>(qtb, ktb, vbb, out);
}